// Round 16
// baseline (311.639 us; speedup 1.0000x reference)
//
#include <hip/hip_runtime.h>

typedef unsigned short u16;
typedef unsigned char u8;
typedef __attribute__((ext_vector_type(16))) float f32x16;

#define B_ROWS 1024
#define DIM 512
#define QN 131072
#define TOPK 32
#define NCLS 10
#define TAUS 35.84f   /* 0.14 * 256 (both operands scaled x16) */
#define CAP 1024
#define FP8SCALE 16.0f

#define S_VMCNT(N) asm volatile("s_waitcnt vmcnt(" #N ")" ::: "memory")
#define S_BAR() asm volatile("s_barrier" ::: "memory")
#define S_LGKM0() asm volatile("s_waitcnt lgkmcnt(0)" ::: "memory")

__device__ __forceinline__ void gload_lds16(const void* gsrc, void* ldst) {
  __builtin_amdgcn_global_load_lds(
      (const __attribute__((address_space(1))) void*)gsrc,
      (__attribute__((address_space(3))) void*)ldst, 16, 0, 0);
}

// pack 4 floats -> 4 fp8 e4m3 bytes (HW cvt). Same packer for A and B, so
// any byte-order convention cancels in the dot product.
__device__ __forceinline__ int pk4(float a, float b, float c, float d) {
  int w = __builtin_amdgcn_cvt_pk_fp8_f32(a, b, 0, false);
  w = __builtin_amdgcn_cvt_pk_fp8_f32(c, d, w, true);
  return w;
}

// ---------------------------------------------------------------- normalize x
// fp32 normalized row -> xn; fp8(x16) k-permuted row -> xnb8; zeroes cnt.
// Permuted layout per 64-k chunk c: 16B slot t = {k c*64+t*8..+8} ++
// {k c*64+32+t*8..+8}.
__global__ __launch_bounds__(256) void normalize_x(const float* __restrict__ x,
                                                   float* __restrict__ xn,
                                                   u8* __restrict__ xnb8,
                                                   int* __restrict__ cnt) {
  int row = blockIdx.x;
  int tid = threadIdx.x;
  __shared__ float xs[DIM];
  __shared__ float wsum[4];
  if (tid == 0) cnt[row] = 0;
  float2 v = ((const float2*)(x + (size_t)row * DIM))[tid];
  float ss = v.x * v.x + v.y * v.y;
  #pragma unroll
  for (int o = 32; o; o >>= 1) ss += __shfl_xor(ss, o);
  if ((tid & 63) == 0) wsum[tid >> 6] = ss;
  __syncthreads();
  float tot = wsum[0] + wsum[1] + wsum[2] + wsum[3];
  float scale = 1.0f / fmaxf(sqrtf(tot), 1e-12f);
  float2 o2; o2.x = v.x * scale; o2.y = v.y * scale;
  ((float2*)(xn + (size_t)row * DIM))[tid] = o2;
  xs[2 * tid] = o2.x; xs[2 * tid + 1] = o2.y;
  __syncthreads();
  if (tid < 32) {  // 32 slots of 16B per row (k-permuted fp8)
    int c = tid >> 2, t4 = tid & 3;
    int k0 = c * 64 + t4 * 8;
    int4 w;
    w.x = pk4(xs[k0+0]*FP8SCALE, xs[k0+1]*FP8SCALE, xs[k0+2]*FP8SCALE, xs[k0+3]*FP8SCALE);
    w.y = pk4(xs[k0+4]*FP8SCALE, xs[k0+5]*FP8SCALE, xs[k0+6]*FP8SCALE, xs[k0+7]*FP8SCALE);
    w.z = pk4(xs[k0+32]*FP8SCALE, xs[k0+33]*FP8SCALE, xs[k0+34]*FP8SCALE, xs[k0+35]*FP8SCALE);
    w.w = pk4(xs[k0+36]*FP8SCALE, xs[k0+37]*FP8SCALE, xs[k0+38]*FP8SCALE, xs[k0+39]*FP8SCALE);
    ((int4*)(xnb8 + (size_t)row * DIM))[tid] = w;
  }
}

// ---------------------- fp8 MFMA GEMM + in-kernel B conversion + filter
// R15 skeleton (proven 187.0us, absmax 0): BM=256 x BN=64, 4 waves, K-step
// 64, A via 2-slot gload_lds queue dist-1, B reg-staged fp32->fp8 2-slot
// ds_write queue dist-2, one s_barrier/step, counted vmcnt, lb(256,4).
// CHANGED (R16):
//  (1) MFMA core -> mfma_f32_32x32x16_fp8_fp8: 16 instrs/step (was 32),
//      same 8 ds_read_b128. Slot t holds k{8t..+8}u{32+8t..+8}; lane
//      g8=lane>>5 reads slots {g8,g8+2} of its row; MFMA instance j=0..3
//      uses (v0.lo, v2.lo, v0.hi, v2.hi) -- instance k-coverage [16j,16j+16)
//      identical for A and B (same layout), so any within-instance k
//      permutation cancels (dot invariance). C/D: col=lane&31,
//      row=(e&3)+8*(e>>2)+4*(lane>>5) (verified R3, m101).
//  (2) Split step: 8 MFMAs (j=0,1) -> vmcnt(4)+writeB(h+1)+issuePB(h+2) ->
//      8 MFMAs (j=2,3) -> lgkm0. PB gains ~half-cluster extra flight; race
//      proofs unchanged (writes hit slot (h+1)&1, reads slot h&1, lgkm0
//      precedes next barrier).
__global__ __launch_bounds__(256, 4) void gemm_filter(const u8* __restrict__ xnb8,
                                                      const float* __restrict__ mem,
                                                      int* __restrict__ cnt,
                                                      int* __restrict__ ccol) {
  __shared__ __attribute__((aligned(16))) u8 As[2][16384];
  __shared__ __attribute__((aligned(16))) u8 Bs[2][4096];
  int bid = blockIdx.x;
  // XCD-aware: the 4 row-sharers of a B-panel sit on one XCD
  int xcd = bid & 7;
  int i = bid >> 3;
  int colt = xcd * 256 + (i >> 2);
  int rowt = i & 3;
  int row0 = rowt * 256;
  int col0 = colt * 64;
  int tid = threadIdx.x;
  int lane = tid & 63;
  int wv = tid >> 6;

  // staging geometry: logical k-slot sg = (tid&3) ^ ((tid>>3)&3); chunk jj
  // covers row r = jj*64 + (tid>>2) -> global offset jj*32768 from base.
  int sg = (tid & 3) ^ ((tid >> 3) & 3);
  const u8* gAb = xnb8 + (size_t)(row0 + (tid >> 2)) * DIM + sg * 16;
  const float* gB = mem + (size_t)(col0 + (tid >> 2)) * DIM + sg * 8;

  // read side: l31 = row/col-within-32, g8 = k-group; q = (row>>1)&3
  int l31 = lane & 31;
  int g8 = lane >> 5;
  int q = (l31 >> 1) & 3;
  int o0 = (g8 ^ q) * 16;          // slot s = g8
  int o2 = ((g8 + 2) ^ q) * 16;    // slot s = g8+2
  int offA = (wv * 64 + l31) * 64; // + m*2048
  int offB = l31 * 64;             // + n*2048

  f32x16 acc[2][2];
  #pragma unroll
  for (int m = 0; m < 2; ++m)
    #pragma unroll
    for (int n = 0; n < 2; ++n)
      #pragma unroll
      for (int e = 0; e < 16; ++e) acc[m][n][e] = 0.f;

  float4 pb[4];  // B prefetch regs: 16 floats (16 VGPR)

  auto stageA = [&](int h) {
    int slot = h & 1;
    #pragma unroll
    for (int jj = 0; jj < 4; ++jj)
      gload_lds16(gAb + (size_t)jj * 32768 + h * 64,
                  &As[slot][jj * 4096 + tid * 16]);
  };
  auto issuePB = [&](int h) {
    const float4* s = (const float4*)(gB + h * 64);
    pb[0] = s[0]; pb[1] = s[1];   // k sg*8..+8
    pb[2] = s[8]; pb[3] = s[9];   // k 32+sg*8..+8
  };
  auto writeB = [&](int h) {
    int slot = h & 1;
    int4 w;
    w.x = pk4(pb[0].x*FP8SCALE, pb[0].y*FP8SCALE, pb[0].z*FP8SCALE, pb[0].w*FP8SCALE);
    w.y = pk4(pb[1].x*FP8SCALE, pb[1].y*FP8SCALE, pb[1].z*FP8SCALE, pb[1].w*FP8SCALE);
    w.z = pk4(pb[2].x*FP8SCALE, pb[2].y*FP8SCALE, pb[2].z*FP8SCALE, pb[2].w*FP8SCALE);
    w.w = pk4(pb[3].x*FP8SCALE, pb[3].y*FP8SCALE, pb[3].z*FP8SCALE, pb[3].w*FP8SCALE);
    *(int4*)&Bs[slot][tid * 16] = w;
  };

  union I4L { int4 v; long l[2]; };

  // prologue: A(0), B(0) resident; PB(1) in flight
  stageA(0); issuePB(0);
  S_VMCNT(0);
  writeB(0);
  issuePB(1);
  S_LGKM0();

  #pragma unroll
  for (int h = 0; h < 8; ++h) {
    if (h < 7) { S_VMCNT(4); }   // retires A(h); keeps PB(h+1) flying
    else { S_VMCNT(0); }         // h=7: drains A(7)
    S_BAR();
    if (h < 7) stageA(h + 1);
    const u8* Ab = &As[h & 1][0];
    const u8* Bb = &Bs[h & 1][0];
    I4L a0[2], a2[2], b0[2], b2[2];
    #pragma unroll
    for (int m = 0; m < 2; ++m) {
      a0[m].v = *(const int4*)(Ab + offA + m * 2048 + o0);
      a2[m].v = *(const int4*)(Ab + offA + m * 2048 + o2);
    }
    #pragma unroll
    for (int n = 0; n < 2; ++n) {
      b0[n].v = *(const int4*)(Bb + offB + n * 2048 + o0);
      b2[n].v = *(const int4*)(Bb + offB + n * 2048 + o2);
    }
    // j=0 (v0.lo), j=1 (v2.lo)
    __builtin_amdgcn_s_setprio(1);
    #pragma unroll
    for (int m = 0; m < 2; ++m)
      #pragma unroll
      for (int n = 0; n < 2; ++n) {
        acc[m][n] = __builtin_amdgcn_mfma_f32_32x32x16_fp8_fp8(
            a0[m].l[0], b0[n].l[0], acc[m][n], 0, 0, 0);
        acc[m][n] = __builtin_amdgcn_mfma_f32_32x32x16_fp8_fp8(
            a2[m].l[0], b2[n].l[0], acc[m][n], 0, 0, 0);
      }
    __builtin_amdgcn_s_setprio(0);
    // mid: retire PB(h+1), convert+write, issue PB(h+2)
    if (h < 7) {
      S_VMCNT(4);                // retires PB(h+1); keeps A(h+1) flying
      writeB(h + 1);
      if (h < 6) issuePB(h + 2);
    }
    // j=2 (v0.hi), j=3 (v2.hi)
    __builtin_amdgcn_s_setprio(1);
    #pragma unroll
    for (int m = 0; m < 2; ++m)
      #pragma unroll
      for (int n = 0; n < 2; ++n) {
        acc[m][n] = __builtin_amdgcn_mfma_f32_32x32x16_fp8_fp8(
            a0[m].l[1], b0[n].l[1], acc[m][n], 0, 0, 0);
        acc[m][n] = __builtin_amdgcn_mfma_f32_32x32x16_fp8_fp8(
            a2[m].l[1], b2[n].l[1], acc[m][n], 0, 0, 0);
      }
    __builtin_amdgcn_s_setprio(0);
    S_LGKM0();   // ds_writes retired before next barrier
  }

  // epilogue: 32x32 C/D layout: col=lane&31, row=(e&3)+8*(e>>2)+4*(lane>>5)
  int rbase = row0 + wv * 64 + 4 * g8;
  int cbase = col0 + l31;
  #pragma unroll
  for (int m = 0; m < 2; ++m)
    #pragma unroll
    for (int n = 0; n < 2; ++n)
      #pragma unroll
      for (int e = 0; e < 16; ++e) {
        float v = acc[m][n][e];
        if (v > TAUS) {
          int grow = rbase + m * 32 + (e & 3) + 8 * (e >> 2);
          int gcol = cbase + n * 32;
          int idx = atomicAdd(&cnt[grow], 1);
          if (idx < CAP) ccol[(size_t)grow * CAP + idx] = gcol;
        }
      }
}

// ------------------------------- exact rescore + top-32 + softmax vote
// (unchanged -- validated absmax 0.0 against the np reference)
__global__ __launch_bounds__(256) void rescore_vote(const float* __restrict__ xn,
                                                    const float* __restrict__ mem,
                                                    const int* __restrict__ labels,
                                                    const int* __restrict__ cnt,
                                                    const int* __restrict__ ccol,
                                                    float* __restrict__ out) {
  int row = blockIdx.x;
  int tid = threadIdx.x;
  int gid = tid >> 4;          // 16 groups
  int gl = tid & 15;           // lane within group
  __shared__ __attribute__((aligned(16))) float xs[DIM];
  __shared__ double sv[CAP];
  __shared__ int sc[CAP];
  __shared__ double selv[TOPK];
  __shared__ int selc[TOPK];
  __shared__ double wv32[TOPK];
  __shared__ int slab[TOPK];

  ((float2*)xs)[tid] = ((const float2*)(xn + (size_t)row * DIM))[tid];
  if (tid < TOPK) { selv[tid] = -1e300; selc[tid] = 0; }
  int count = cnt[row];
  if (count > CAP) count = CAP;
  __syncthreads();

  // dot phase: one 16-lane group per candidate, fp64 accumulate
  for (int c = gid; c < count; c += 16) {
    int col = ccol[(size_t)row * CAP + c];
    const float4* mp = (const float4*)(mem + (size_t)col * DIM);
    const float4* xp = (const float4*)xs;
    double p = 0.0;
    #pragma unroll
    for (int u = 0; u < 8; ++u) {
      float4 mv = mp[u * 16 + gl];
      float4 xv = xp[u * 16 + gl];
      p += (double)mv.x * xv.x + (double)mv.y * xv.y +
           (double)mv.z * xv.z + (double)mv.w * xv.w;
    }
    #pragma unroll
    for (int o = 8; o; o >>= 1) p += __shfl_xor(p, o);
    if (gl == 0) { sv[c] = p; sc[c] = col; }
  }
  __syncthreads();

  // rank-based top-32: rank = #{j: v_j > v or (v_j==v && col_j < col)}
  for (int c = tid; c < count; c += 256) {
    double v = sv[c]; int cc = sc[c];
    int r = 0;
    for (int j = 0; j < count; ++j) {
      double vj = sv[j]; int cj = sc[j];
      r += (vj > v) || (vj == v && cj < cc);
    }
    if (r < TOPK) { selv[r] = v; selc[r] = cc; }
  }
  __syncthreads();

  // softmax(sim/0.1) + one-hot vote
  if (tid < TOPK) {
    slab[tid] = labels[selc[tid]];
    double e = exp((selv[tid] - selv[0]) * 10.0);
    double s = e;
    #pragma unroll
    for (int o = 16; o; o >>= 1) s += __shfl_xor(s, o, 32);
    wv32[tid] = e / s;
  }
  __syncthreads();
  if (tid < NCLS) {
    double a = 0.0;
    #pragma unroll
    for (int k = 0; k < TOPK; ++k)
      if (slab[k] == tid) a += wv32[k];
    float r2 = (float)(a + 1e-5);
    out[(size_t)row * NCLS + tid] = fminf(r2, 1.0f);
  }
}

// ---------------------------------------------------------------------------
extern "C" void kernel_launch(void* const* d_in, const int* in_sizes, int n_in,
                              void* d_out, int out_size, void* d_ws, size_t ws_size,
                              hipStream_t stream) {
  const float* x = (const float*)d_in[0];
  const float* mem = (const float*)d_in[1];
  const int* labels = (const int*)d_in[2];
  float* out = (float*)d_out;
  char* ws = (char*)d_ws;

  // workspace layout (needs ~7 MB)
  float* xn = (float*)ws;                            //   2,097,152 B
  u8* xnb8 = (u8*)(ws + 2097152);                    //     524,288 B
  int* cnt = (int*)(ws + 2621440);                   //       4,096 B
  int* ccol = (int*)(ws + 2625536);                  //   4,194,304 B

  normalize_x<<<dim3(B_ROWS), dim3(256), 0, stream>>>(x, xn, xnb8, cnt);
  gemm_filter<<<dim3((B_ROWS / 256) * (QN / 64)), dim3(256), 0, stream>>>(
      xnb8, mem, cnt, ccol);
  rescore_vote<<<dim3(B_ROWS), dim3(256), 0, stream>>>(xn, mem, labels, cnt,
                                                       ccol, out);
}

// Round 17
// 212.440 us; speedup vs baseline: 1.4669x; 1.4669x over previous
//
#include <hip/hip_runtime.h>

typedef unsigned short u16;
typedef unsigned char u8;
typedef __attribute__((ext_vector_type(4))) float f32x4;

#define B_ROWS 1024
#define DIM 512
#define QN 131072
#define TOPK 32
#define NCLS 10
#define TAUS 35.84f   /* 0.14 * 256 (both operands scaled x16) */
#define CAP 1024
#define FP8SCALE 16.0f

#define S_VMCNT(N) asm volatile("s_waitcnt vmcnt(" #N ")" ::: "memory")
#define S_BAR() asm volatile("s_barrier" ::: "memory")
#define S_LGKM0() asm volatile("s_waitcnt lgkmcnt(0)" ::: "memory")

__device__ __forceinline__ void gload_lds16(const void* gsrc, void* ldst) {
  __builtin_amdgcn_global_load_lds(
      (const __attribute__((address_space(1))) void*)gsrc,
      (__attribute__((address_space(3))) void*)ldst, 16, 0, 0);
}

// pack 4 floats -> 4 fp8 e4m3 bytes (HW cvt). Same packer for A and B, so
// any byte-order convention cancels in the dot product.
__device__ __forceinline__ int pk4(float a, float b, float c, float d) {
  int w = __builtin_amdgcn_cvt_pk_fp8_f32(a, b, 0, false);
  w = __builtin_amdgcn_cvt_pk_fp8_f32(c, d, w, true);
  return w;
}

// ---------------------------------------------------------------- normalize x
// fp32 normalized row -> xn; fp8(x16) k-permuted row -> xnb8; zeroes cnt.
// Permuted layout per 64-k chunk c: 16B slot t = {k c*64+t*8..+8} ++
// {k c*64+32+t*8..+8}.
__global__ __launch_bounds__(256) void normalize_x(const float* __restrict__ x,
                                                   float* __restrict__ xn,
                                                   u8* __restrict__ xnb8,
                                                   int* __restrict__ cnt) {
  int row = blockIdx.x;
  int tid = threadIdx.x;
  __shared__ float xs[DIM];
  __shared__ float wsum[4];
  if (tid == 0) cnt[row] = 0;
  float2 v = ((const float2*)(x + (size_t)row * DIM))[tid];
  float ss = v.x * v.x + v.y * v.y;
  #pragma unroll
  for (int o = 32; o; o >>= 1) ss += __shfl_xor(ss, o);
  if ((tid & 63) == 0) wsum[tid >> 6] = ss;
  __syncthreads();
  float tot = wsum[0] + wsum[1] + wsum[2] + wsum[3];
  float scale = 1.0f / fmaxf(sqrtf(tot), 1e-12f);
  float2 o2; o2.x = v.x * scale; o2.y = v.y * scale;
  ((float2*)(xn + (size_t)row * DIM))[tid] = o2;
  xs[2 * tid] = o2.x; xs[2 * tid + 1] = o2.y;
  __syncthreads();
  if (tid < 32) {  // 32 slots of 16B per row (k-permuted fp8)
    int c = tid >> 2, t4 = tid & 3;
    int k0 = c * 64 + t4 * 8;
    int4 w;
    w.x = pk4(xs[k0+0]*FP8SCALE, xs[k0+1]*FP8SCALE, xs[k0+2]*FP8SCALE, xs[k0+3]*FP8SCALE);
    w.y = pk4(xs[k0+4]*FP8SCALE, xs[k0+5]*FP8SCALE, xs[k0+6]*FP8SCALE, xs[k0+7]*FP8SCALE);
    w.z = pk4(xs[k0+32]*FP8SCALE, xs[k0+33]*FP8SCALE, xs[k0+34]*FP8SCALE, xs[k0+35]*FP8SCALE);
    w.w = pk4(xs[k0+36]*FP8SCALE, xs[k0+37]*FP8SCALE, xs[k0+38]*FP8SCALE, xs[k0+39]*FP8SCALE);
    ((int4*)(xnb8 + (size_t)row * DIM))[tid] = w;
  }
}

// ---------------------- fp8 MFMA GEMM + in-kernel B conversion + filter
// R15 VERBATIM (proven 187.0us, absmax 0; 16x16x32 fp8, BM=256 x BN=64,
// 4 waves, K-step 64, A 2-slot gload_lds dist-1, B reg-staged 2-slot
// ds_write dist-2, one s_barrier/step, counted vmcnt, lb(256,4)) except:
//  (1) mid-step B-write: vmcnt(4)+writeB(h+1)+issuePB(h+2) sits BETWEEN the
//      two 16-MFMA halves (l[0] then l[1]) -- PB(h+2) gains flight, cvt
//      VALU overlaps MFMA. No new live regs (av/bv span both halves
//      anyway; pb dies earlier). Race proofs unchanged: writes hit slot
//      (h+1)&1, reads slot h&1, lgkm0 precedes next barrier.
//  (2) s_setprio removed (m190: negative on lockstep GEMM; T5 needs
//      role-split which this schedule doesn't have).
// NOTE (R13/R16 lesson): 32x32 fp8 shapes are incompatible with this
// k-permuted 64B-row layout -- both attempts produced 8.4e6 bank conflicts
// + scratch spill. Do not retry.
__global__ __launch_bounds__(256, 4) void gemm_filter(const u8* __restrict__ xnb8,
                                                      const float* __restrict__ mem,
                                                      int* __restrict__ cnt,
                                                      int* __restrict__ ccol) {
  __shared__ __attribute__((aligned(16))) u8 As[2][16384];
  __shared__ __attribute__((aligned(16))) u8 Bs[2][4096];
  int bid = blockIdx.x;
  // XCD-aware: the 4 row-sharers of a B-panel sit on one XCD
  int xcd = bid & 7;
  int i = bid >> 3;
  int colt = xcd * 256 + (i >> 2);
  int rowt = i & 3;
  int row0 = rowt * 256;
  int col0 = colt * 64;
  int tid = threadIdx.x;
  int lane = tid & 63;
  int wv = tid >> 6;

  // staging geometry: logical k-slot sg = (tid&3) ^ ((tid>>3)&3); chunk jj
  // covers row r = jj*64 + (tid>>2) -> global offset jj*32768 from base.
  int sg = (tid & 3) ^ ((tid >> 3) & 3);
  const u8* gAb = xnb8 + (size_t)(row0 + (tid >> 2)) * DIM + sg * 16;
  const float* gB = mem + (size_t)(col0 + (tid >> 2)) * DIM + sg * 8;

  // read side: lane L = row-within-16; phys slot = g ^ ((L>>1)&3)
  int L = lane & 15;
  int g = lane >> 4;
  int phys = g ^ ((L >> 1) & 3);
  int offA = (wv * 64 + L) * 64 + phys * 16;   // bytes, + m*1024
  int offB = L * 64 + phys * 16;               // bytes, + n*1024

  f32x4 acc[4][4];
  #pragma unroll
  for (int m = 0; m < 4; ++m)
    #pragma unroll
    for (int n = 0; n < 4; ++n) acc[m][n] = (f32x4){0.f, 0.f, 0.f, 0.f};

  float4 pb[4];  // B prefetch regs: 16 floats (16 VGPR)

  auto stageA = [&](int h) {
    int slot = h & 1;
    #pragma unroll
    for (int jj = 0; jj < 4; ++jj)
      gload_lds16(gAb + (size_t)jj * 32768 + h * 64,
                  &As[slot][jj * 4096 + tid * 16]);
  };
  auto issuePB = [&](int h) {
    const float4* s = (const float4*)(gB + h * 64);
    pb[0] = s[0]; pb[1] = s[1];   // k sg*8..+8
    pb[2] = s[8]; pb[3] = s[9];   // k 32+sg*8..+8
  };
  auto writeB = [&](int h) {
    int slot = h & 1;
    int4 w;
    w.x = pk4(pb[0].x*FP8SCALE, pb[0].y*FP8SCALE, pb[0].z*FP8SCALE, pb[0].w*FP8SCALE);
    w.y = pk4(pb[1].x*FP8SCALE, pb[1].y*FP8SCALE, pb[1].z*FP8SCALE, pb[1].w*FP8SCALE);
    w.z = pk4(pb[2].x*FP8SCALE, pb[2].y*FP8SCALE, pb[2].z*FP8SCALE, pb[2].w*FP8SCALE);
    w.w = pk4(pb[3].x*FP8SCALE, pb[3].y*FP8SCALE, pb[3].z*FP8SCALE, pb[3].w*FP8SCALE);
    *(int4*)&Bs[slot][tid * 16] = w;
  };

  union I4L { int4 v; long l[2]; };

  // prologue: A(0), B(0) resident; PB(1) in flight
  stageA(0); issuePB(0);
  S_VMCNT(0);
  writeB(0);
  issuePB(1);
  S_LGKM0();

  #pragma unroll
  for (int h = 0; h < 8; ++h) {
    if (h < 7) { S_VMCNT(4); }   // retires A(h); keeps PB(h+1) flying
    else { S_VMCNT(0); }         // h=7: drains A(7)
    S_BAR();
    if (h < 7) stageA(h + 1);
    const u8* Ab = &As[h & 1][0];
    const u8* Bb = &Bs[h & 1][0];
    I4L av[4], bv[4];
    #pragma unroll
    for (int m = 0; m < 4; ++m) av[m].v = *(const int4*)(Ab + offA + m * 1024);
    #pragma unroll
    for (int n = 0; n < 4; ++n) bv[n].v = *(const int4*)(Bb + offB + n * 1024);
    // first 16 MFMAs (k-half 0)
    #pragma unroll
    for (int m = 0; m < 4; ++m)
      #pragma unroll
      for (int n = 0; n < 4; ++n)
        acc[m][n] = __builtin_amdgcn_mfma_f32_16x16x32_fp8_fp8(
            av[m].l[0], bv[n].l[0], acc[m][n], 0, 0, 0);
    // mid: retire PB(h+1), convert+write, issue PB(h+2) -- overlaps MFMA
    if (h < 7) {
      S_VMCNT(4);                // retires PB(h+1); keeps A(h+1) flying
      writeB(h + 1);
      if (h < 6) issuePB(h + 2);
    }
    // second 16 MFMAs (k-half 1)
    #pragma unroll
    for (int m = 0; m < 4; ++m)
      #pragma unroll
      for (int n = 0; n < 4; ++n)
        acc[m][n] = __builtin_amdgcn_mfma_f32_16x16x32_fp8_fp8(
            av[m].l[1], bv[n].l[1], acc[m][n], 0, 0, 0);
    S_LGKM0();                   // ds ops retired before next barrier
  }

  // epilogue: D row=(lane>>4)*4+q, col=lane&15 (dtype-independent layout)
  int rbase = row0 + wv * 64 + (lane >> 4) * 4;
  int cbase = col0 + (lane & 15);
  #pragma unroll
  for (int m = 0; m < 4; ++m)
    #pragma unroll
    for (int n = 0; n < 4; ++n)
      #pragma unroll
      for (int q = 0; q < 4; ++q) {
        float v = acc[m][n][q];
        if (v > TAUS) {
          int grow = rbase + m * 16 + q;
          int gcol = cbase + n * 16;
          int idx = atomicAdd(&cnt[grow], 1);
          if (idx < CAP) ccol[(size_t)grow * CAP + idx] = gcol;
        }
      }
}

// ------------------------------- exact rescore + top-32 + softmax vote
// (R15-validated logic; dot phase now 8-lane groups: 32 candidates in
// flight vs 16 -- same bytes/math, double memory-level parallelism)
__global__ __launch_bounds__(256) void rescore_vote(const float* __restrict__ xn,
                                                    const float* __restrict__ mem,
                                                    const int* __restrict__ labels,
                                                    const int* __restrict__ cnt,
                                                    const int* __restrict__ ccol,
                                                    float* __restrict__ out) {
  int row = blockIdx.x;
  int tid = threadIdx.x;
  int gid = tid >> 3;          // 32 groups of 8 lanes
  int gl = tid & 7;            // lane within group
  __shared__ __attribute__((aligned(16))) float xs[DIM];
  __shared__ double sv[CAP];
  __shared__ int sc[CAP];
  __shared__ double selv[TOPK];
  __shared__ int selc[TOPK];
  __shared__ double wv32[TOPK];
  __shared__ int slab[TOPK];

  ((float2*)xs)[tid] = ((const float2*)(xn + (size_t)row * DIM))[tid];
  if (tid < TOPK) { selv[tid] = -1e300; selc[tid] = 0; }
  int count = cnt[row];
  if (count > CAP) count = CAP;
  __syncthreads();

  // dot phase: one 8-lane group per candidate, fp64 accumulate.
  // lane gl covers float4 indices u*8+gl, u=0..15 (contiguous 128B/instr)
  for (int c = gid; c < count; c += 32) {
    int col = ccol[(size_t)row * CAP + c];
    const float4* mp = (const float4*)(mem + (size_t)col * DIM);
    const float4* xp = (const float4*)xs;
    double p = 0.0;
    #pragma unroll
    for (int u = 0; u < 16; ++u) {
      float4 mv = mp[u * 8 + gl];
      float4 xv = xp[u * 8 + gl];
      p += (double)mv.x * xv.x + (double)mv.y * xv.y +
           (double)mv.z * xv.z + (double)mv.w * xv.w;
    }
    #pragma unroll
    for (int o = 4; o; o >>= 1) p += __shfl_xor(p, o);
    if (gl == 0) { sv[c] = p; sc[c] = col; }
  }
  __syncthreads();

  // rank-based top-32: rank = #{j: v_j > v or (v_j==v && col_j < col)}
  for (int c = tid; c < count; c += 256) {
    double v = sv[c]; int cc = sc[c];
    int r = 0;
    for (int j = 0; j < count; ++j) {
      double vj = sv[j]; int cj = sc[j];
      r += (vj > v) || (vj == v && cj < cc);
    }
    if (r < TOPK) { selv[r] = v; selc[r] = cc; }
  }
  __syncthreads();

  // softmax(sim/0.1) + one-hot vote
  if (tid < TOPK) {
    slab[tid] = labels[selc[tid]];
    double e = exp((selv[tid] - selv[0]) * 10.0);
    double s = e;
    #pragma unroll
    for (int o = 16; o; o >>= 1) s += __shfl_xor(s, o, 32);
    wv32[tid] = e / s;
  }
  __syncthreads();
  if (tid < NCLS) {
    double a = 0.0;
    #pragma unroll
    for (int k = 0; k < TOPK; ++k)
      if (slab[k] == tid) a += wv32[k];
    float r2 = (float)(a + 1e-5);
    out[(size_t)row * NCLS + tid] = fminf(r2, 1.0f);
  }
}

// ---------------------------------------------------------------------------
extern "C" void kernel_launch(void* const* d_in, const int* in_sizes, int n_in,
                              void* d_out, int out_size, void* d_ws, size_t ws_size,
                              hipStream_t stream) {
  const float* x = (const float*)d_in[0];
  const float* mem = (const float*)d_in[1];
  const int* labels = (const int*)d_in[2];
  float* out = (float*)d_out;
  char* ws = (char*)d_ws;

  // workspace layout (needs ~7 MB)
  float* xn = (float*)ws;                            //   2,097,152 B
  u8* xnb8 = (u8*)(ws + 2097152);                    //     524,288 B
  int* cnt = (int*)(ws + 2621440);                   //       4,096 B
  int* ccol = (int*)(ws + 2625536);                  //   4,194,304 B

  normalize_x<<<dim3(B_ROWS), dim3(256), 0, stream>>>(x, xn, xnb8, cnt);
  gemm_filter<<<dim3((B_ROWS / 256) * (QN / 64)), dim3(256), 0, stream>>>(
      xnb8, mem, cnt, ccol);
  rescore_vote<<<dim3(B_ROWS), dim3(256), 0, stream>>>(xn, mem, labels, cnt,
                                                       ccol, out);
}

// Round 18
// 183.865 us; speedup vs baseline: 1.6949x; 1.1554x over previous
//
#include <hip/hip_runtime.h>

typedef unsigned short u16;
typedef unsigned char u8;
typedef __attribute__((ext_vector_type(4))) float f32x4;

#define B_ROWS 1024
#define DIM 512
#define QN 131072
#define TOPK 32
#define NCLS 10
#define TAUS 35.84f   /* 0.14 * 256 (both operands scaled x16) */
#define CAP 1024
#define FP8SCALE 16.0f

#define S_VMCNT(N) asm volatile("s_waitcnt vmcnt(" #N ")" ::: "memory")
#define S_BAR() asm volatile("s_barrier" ::: "memory")
#define S_LGKM0() asm volatile("s_waitcnt lgkmcnt(0)" ::: "memory")

__device__ __forceinline__ void gload_lds16(const void* gsrc, void* ldst) {
  __builtin_amdgcn_global_load_lds(
      (const __attribute__((address_space(1))) void*)gsrc,
      (__attribute__((address_space(3))) void*)ldst, 16, 0, 0);
}

// pack 4 floats -> 4 fp8 e4m3 bytes (HW cvt). Same packer for A and B, so
// any byte-order convention cancels in the dot product.
__device__ __forceinline__ int pk4(float a, float b, float c, float d) {
  int w = __builtin_amdgcn_cvt_pk_fp8_f32(a, b, 0, false);
  w = __builtin_amdgcn_cvt_pk_fp8_f32(c, d, w, true);
  return w;
}

// ---------------------------------------------------------------- normalize x
// fp32 normalized row -> xn; fp8(x16) k-permuted row -> xnb8; zeroes cnt.
// Permuted layout per 64-k chunk c: 16B slot t = {k c*64+t*8..+8} ++
// {k c*64+32+t*8..+8}.
__global__ __launch_bounds__(256) void normalize_x(const float* __restrict__ x,
                                                   float* __restrict__ xn,
                                                   u8* __restrict__ xnb8,
                                                   int* __restrict__ cnt) {
  int row = blockIdx.x;
  int tid = threadIdx.x;
  __shared__ float xs[DIM];
  __shared__ float wsum[4];
  if (tid == 0) cnt[row] = 0;
  float2 v = ((const float2*)(x + (size_t)row * DIM))[tid];
  float ss = v.x * v.x + v.y * v.y;
  #pragma unroll
  for (int o = 32; o; o >>= 1) ss += __shfl_xor(ss, o);
  if ((tid & 63) == 0) wsum[tid >> 6] = ss;
  __syncthreads();
  float tot = wsum[0] + wsum[1] + wsum[2] + wsum[3];
  float scale = 1.0f / fmaxf(sqrtf(tot), 1e-12f);
  float2 o2; o2.x = v.x * scale; o2.y = v.y * scale;
  ((float2*)(xn + (size_t)row * DIM))[tid] = o2;
  xs[2 * tid] = o2.x; xs[2 * tid + 1] = o2.y;
  __syncthreads();
  if (tid < 32) {  // 32 slots of 16B per row (k-permuted fp8)
    int c = tid >> 2, t4 = tid & 3;
    int k0 = c * 64 + t4 * 8;
    int4 w;
    w.x = pk4(xs[k0+0]*FP8SCALE, xs[k0+1]*FP8SCALE, xs[k0+2]*FP8SCALE, xs[k0+3]*FP8SCALE);
    w.y = pk4(xs[k0+4]*FP8SCALE, xs[k0+5]*FP8SCALE, xs[k0+6]*FP8SCALE, xs[k0+7]*FP8SCALE);
    w.z = pk4(xs[k0+32]*FP8SCALE, xs[k0+33]*FP8SCALE, xs[k0+34]*FP8SCALE, xs[k0+35]*FP8SCALE);
    w.w = pk4(xs[k0+36]*FP8SCALE, xs[k0+37]*FP8SCALE, xs[k0+38]*FP8SCALE, xs[k0+39]*FP8SCALE);
    ((int4*)(xnb8 + (size_t)row * DIM))[tid] = w;
  }
}

// ---------------------- fp8 MFMA GEMM + in-kernel B conversion + filter
// R15 VERBATIM (proven 187.0us, absmax 0; 16x16x32 fp8, BM=256 x BN=64,
// 4 waves, K-step 64, A 2-slot gload_lds dist-1, B reg-staged 2-slot
// ds_write dist-2, one s_barrier/step, counted vmcnt, lb(256,4), setprio
// around MFMA cluster, writeB at end-of-step) except one prologue fix:
// issuePB(0) BEFORE stageA(0), then vmcnt(4) -- retires PB(0) exactly
// (oldest-first), A(0) keeps flying into loop-h0's vmcnt(4) which retires
// it there (identical steady-state invariants). No forced full drain.
// Race proofs unchanged: writeB(0) visibility = prologue lgkm0 + h0 barrier.
// NOTE (R13/R16 lesson): 32x32 fp8 shapes are incompatible with this
// k-permuted 64B-row layout (8.4e6 conflicts + spill, twice). Do not retry.
// NOTE (R17 lesson): mid-step writeB and setprio-removal both regress;
// rescore 8-lane groups regress (~+19us). Keep R15 forms.
__global__ __launch_bounds__(256, 4) void gemm_filter(const u8* __restrict__ xnb8,
                                                      const float* __restrict__ mem,
                                                      int* __restrict__ cnt,
                                                      int* __restrict__ ccol) {
  __shared__ __attribute__((aligned(16))) u8 As[2][16384];
  __shared__ __attribute__((aligned(16))) u8 Bs[2][4096];
  int bid = blockIdx.x;
  // XCD-aware: the 4 row-sharers of a B-panel sit on one XCD
  int xcd = bid & 7;
  int i = bid >> 3;
  int colt = xcd * 256 + (i >> 2);
  int rowt = i & 3;
  int row0 = rowt * 256;
  int col0 = colt * 64;
  int tid = threadIdx.x;
  int lane = tid & 63;
  int wv = tid >> 6;

  // staging geometry: logical k-slot sg = (tid&3) ^ ((tid>>3)&3); chunk jj
  // covers row r = jj*64 + (tid>>2) -> global offset jj*32768 from base.
  int sg = (tid & 3) ^ ((tid >> 3) & 3);
  const u8* gAb = xnb8 + (size_t)(row0 + (tid >> 2)) * DIM + sg * 16;
  const float* gB = mem + (size_t)(col0 + (tid >> 2)) * DIM + sg * 8;

  // read side: lane L = row-within-16; phys slot = g ^ ((L>>1)&3)
  int L = lane & 15;
  int g = lane >> 4;
  int phys = g ^ ((L >> 1) & 3);
  int offA = (wv * 64 + L) * 64 + phys * 16;   // bytes, + m*1024
  int offB = L * 64 + phys * 16;               // bytes, + n*1024

  f32x4 acc[4][4];
  #pragma unroll
  for (int m = 0; m < 4; ++m)
    #pragma unroll
    for (int n = 0; n < 4; ++n) acc[m][n] = (f32x4){0.f, 0.f, 0.f, 0.f};

  float4 pb[4];  // B prefetch regs: 16 floats (16 VGPR)

  auto stageA = [&](int h) {
    int slot = h & 1;
    #pragma unroll
    for (int jj = 0; jj < 4; ++jj)
      gload_lds16(gAb + (size_t)jj * 32768 + h * 64,
                  &As[slot][jj * 4096 + tid * 16]);
  };
  auto issuePB = [&](int h) {
    const float4* s = (const float4*)(gB + h * 64);
    pb[0] = s[0]; pb[1] = s[1];   // k sg*8..+8
    pb[2] = s[8]; pb[3] = s[9];   // k 32+sg*8..+8
  };
  auto writeB = [&](int h) {
    int slot = h & 1;
    int4 w;
    w.x = pk4(pb[0].x*FP8SCALE, pb[0].y*FP8SCALE, pb[0].z*FP8SCALE, pb[0].w*FP8SCALE);
    w.y = pk4(pb[1].x*FP8SCALE, pb[1].y*FP8SCALE, pb[1].z*FP8SCALE, pb[1].w*FP8SCALE);
    w.z = pk4(pb[2].x*FP8SCALE, pb[2].y*FP8SCALE, pb[2].z*FP8SCALE, pb[2].w*FP8SCALE);
    w.w = pk4(pb[3].x*FP8SCALE, pb[3].y*FP8SCALE, pb[3].z*FP8SCALE, pb[3].w*FP8SCALE);
    *(int4*)&Bs[slot][tid * 16] = w;
  };

  union I4L { int4 v; long l[2]; };

  // prologue: PB(0) first, then A(0); vmcnt(4) retires PB(0) only (A(0)
  // keeps flying -- retired by loop-h0's vmcnt(4)+barrier).
  issuePB(0); stageA(0);
  S_VMCNT(4);
  writeB(0);
  issuePB(1);
  S_LGKM0();

  #pragma unroll
  for (int h = 0; h < 8; ++h) {
    if (h < 7) { S_VMCNT(4); }   // retires A(h); keeps PB(h+1) flying
    else { S_VMCNT(0); }         // h=7: drains A(7)
    S_BAR();
    if (h < 7) stageA(h + 1);
    const u8* Ab = &As[h & 1][0];
    const u8* Bb = &Bs[h & 1][0];
    I4L av[4], bv[4];
    #pragma unroll
    for (int m = 0; m < 4; ++m) av[m].v = *(const int4*)(Ab + offA + m * 1024);
    #pragma unroll
    for (int n = 0; n < 4; ++n) bv[n].v = *(const int4*)(Bb + offB + n * 1024);
    __builtin_amdgcn_s_setprio(1);
    #pragma unroll
    for (int m = 0; m < 4; ++m)
      #pragma unroll
      for (int n = 0; n < 4; ++n)
        acc[m][n] = __builtin_amdgcn_mfma_f32_16x16x32_fp8_fp8(
            av[m].l[0], bv[n].l[0], acc[m][n], 0, 0, 0);
    #pragma unroll
    for (int m = 0; m < 4; ++m)
      #pragma unroll
      for (int n = 0; n < 4; ++n)
        acc[m][n] = __builtin_amdgcn_mfma_f32_16x16x32_fp8_fp8(
            av[m].l[1], bv[n].l[1], acc[m][n], 0, 0, 0);
    __builtin_amdgcn_s_setprio(0);
    if (h < 7) {
      S_VMCNT(4);                // retires PB(h+1); keeps A(h+1) flying
      writeB(h + 1);
      if (h < 6) issuePB(h + 2);
      S_LGKM0();                 // ds ops retired before next barrier
    }
  }

  // epilogue: D row=(lane>>4)*4+q, col=lane&15 (dtype-independent layout)
  int rbase = row0 + wv * 64 + (lane >> 4) * 4;
  int cbase = col0 + (lane & 15);
  #pragma unroll
  for (int m = 0; m < 4; ++m)
    #pragma unroll
    for (int n = 0; n < 4; ++n)
      #pragma unroll
      for (int q = 0; q < 4; ++q) {
        float v = acc[m][n][q];
        if (v > TAUS) {
          int grow = rbase + m * 16 + q;
          int gcol = cbase + n * 16;
          int idx = atomicAdd(&cnt[grow], 1);
          if (idx < CAP) ccol[(size_t)grow * CAP + idx] = gcol;
        }
      }
}

// ------------------------------- exact rescore + top-32 + softmax vote
// (R15 VERBATIM -- validated absmax 0.0; 16-lane groups: R17 showed 8-lane
// regresses ~+19us)
__global__ __launch_bounds__(256) void rescore_vote(const float* __restrict__ xn,
                                                    const float* __restrict__ mem,
                                                    const int* __restrict__ labels,
                                                    const int* __restrict__ cnt,
                                                    const int* __restrict__ ccol,
                                                    float* __restrict__ out) {
  int row = blockIdx.x;
  int tid = threadIdx.x;
  int gid = tid >> 4;          // 16 groups
  int gl = tid & 15;           // lane within group
  __shared__ __attribute__((aligned(16))) float xs[DIM];
  __shared__ double sv[CAP];
  __shared__ int sc[CAP];
  __shared__ double selv[TOPK];
  __shared__ int selc[TOPK];
  __shared__ double wv32[TOPK];
  __shared__ int slab[TOPK];

  ((float2*)xs)[tid] = ((const float2*)(xn + (size_t)row * DIM))[tid];
  if (tid < TOPK) { selv[tid] = -1e300; selc[tid] = 0; }
  int count = cnt[row];
  if (count > CAP) count = CAP;
  __syncthreads();

  // dot phase: one 16-lane group per candidate, fp64 accumulate
  for (int c = gid; c < count; c += 16) {
    int col = ccol[(size_t)row * CAP + c];
    const float4* mp = (const float4*)(mem + (size_t)col * DIM);
    const float4* xp = (const float4*)xs;
    double p = 0.0;
    #pragma unroll
    for (int u = 0; u < 8; ++u) {
      float4 mv = mp[u * 16 + gl];
      float4 xv = xp[u * 16 + gl];
      p += (double)mv.x * xv.x + (double)mv.y * xv.y +
           (double)mv.z * xv.z + (double)mv.w * xv.w;
    }
    #pragma unroll
    for (int o = 8; o; o >>= 1) p += __shfl_xor(p, o);
    if (gl == 0) { sv[c] = p; sc[c] = col; }
  }
  __syncthreads();

  // rank-based top-32: rank = #{j: v_j > v or (v_j==v && col_j < col)}
  for (int c = tid; c < count; c += 256) {
    double v = sv[c]; int cc = sc[c];
    int r = 0;
    for (int j = 0; j < count; ++j) {
      double vj = sv[j]; int cj = sc[j];
      r += (vj > v) || (vj == v && cj < cc);
    }
    if (r < TOPK) { selv[r] = v; selc[r] = cc; }
  }
  __syncthreads();

  // softmax(sim/0.1) + one-hot vote
  if (tid < TOPK) {
    slab[tid] = labels[selc[tid]];
    double e = exp((selv[tid] - selv[0]) * 10.0);
    double s = e;
    #pragma unroll
    for (int o = 16; o; o >>= 1) s += __shfl_xor(s, o, 32);
    wv32[tid] = e / s;
  }
  __syncthreads();
  if (tid < NCLS) {
    double a = 0.0;
    #pragma unroll
    for (int k = 0; k < TOPK; ++k)
      if (slab[k] == tid) a += wv32[k];
    float r2 = (float)(a + 1e-5);
    out[(size_t)row * NCLS + tid] = fminf(r2, 1.0f);
  }
}

// ---------------------------------------------------------------------------
extern "C" void kernel_launch(void* const* d_in, const int* in_sizes, int n_in,
                              void* d_out, int out_size, void* d_ws, size_t ws_size,
                              hipStream_t stream) {
  const float* x = (const float*)d_in[0];
  const float* mem = (const float*)d_in[1];
  const int* labels = (const int*)d_in[2];
  float* out = (float*)d_out;
  char* ws = (char*)d_ws;

  // workspace layout (needs ~7 MB)
  float* xn = (float*)ws;                            //   2,097,152 B
  u8* xnb8 = (u8*)(ws + 2097152);                    //     524,288 B
  int* cnt = (int*)(ws + 2621440);                   //       4,096 B
  int* ccol = (int*)(ws + 2625536);                  //   4,194,304 B

  normalize_x<<<dim3(B_ROWS), dim3(256), 0, stream>>>(x, xn, xnb8, cnt);
  gemm_filter<<<dim3((B_ROWS / 256) * (QN / 64)), dim3(256), 0, stream>>>(
      xnb8, mem, cnt, ccol);
  rescore_vote<<<dim3(B_ROWS), dim3(256), 0, stream>>>(xn, mem, labels, cnt,
                                                       ccol, out);
}

// Round 19
// 177.357 us; speedup vs baseline: 1.7571x; 1.0367x over previous
//
#include <hip/hip_runtime.h>

typedef unsigned short u16;
typedef unsigned char u8;
typedef __attribute__((ext_vector_type(4))) float f32x4;

#define B_ROWS 1024
#define DIM 512
#define QN 131072
#define TOPK 32
#define NCLS 10
#define TAUS 35.84f   /* 0.14 * 256 (both operands scaled x16) */
#define CAP 1024
#define FP8SCALE 16.0f

#define S_VMCNT(N) asm volatile("s_waitcnt vmcnt(" #N ")" ::: "memory")
#define S_BAR() asm volatile("s_barrier" ::: "memory")
#define S_LGKM0() asm volatile("s_waitcnt lgkmcnt(0)" ::: "memory")

__device__ __forceinline__ void gload_lds16(const void* gsrc, void* ldst) {
  __builtin_amdgcn_global_load_lds(
      (const __attribute__((address_space(1))) void*)gsrc,
      (__attribute__((address_space(3))) void*)ldst, 16, 0, 0);
}

// pack 4 floats -> 4 fp8 e4m3 bytes (HW cvt). Same packer for A and B, so
// any byte-order convention cancels in the dot product.
__device__ __forceinline__ int pk4(float a, float b, float c, float d) {
  int w = __builtin_amdgcn_cvt_pk_fp8_f32(a, b, 0, false);
  w = __builtin_amdgcn_cvt_pk_fp8_f32(c, d, w, true);
  return w;
}

// ---------------------------------------------------------------- normalize x
// fp32 normalized row -> xn; fp8(x16) k-permuted row -> xnb8; zeroes cnt.
// Permuted layout per 64-k chunk c: 16B slot t = {k c*64+t*8..+8} ++
// {k c*64+32+t*8..+8}.
__global__ __launch_bounds__(256) void normalize_x(const float* __restrict__ x,
                                                   float* __restrict__ xn,
                                                   u8* __restrict__ xnb8,
                                                   int* __restrict__ cnt) {
  int row = blockIdx.x;
  int tid = threadIdx.x;
  __shared__ float xs[DIM];
  __shared__ float wsum[4];
  if (tid == 0) cnt[row] = 0;
  float2 v = ((const float2*)(x + (size_t)row * DIM))[tid];
  float ss = v.x * v.x + v.y * v.y;
  #pragma unroll
  for (int o = 32; o; o >>= 1) ss += __shfl_xor(ss, o);
  if ((tid & 63) == 0) wsum[tid >> 6] = ss;
  __syncthreads();
  float tot = wsum[0] + wsum[1] + wsum[2] + wsum[3];
  float scale = 1.0f / fmaxf(sqrtf(tot), 1e-12f);
  float2 o2; o2.x = v.x * scale; o2.y = v.y * scale;
  ((float2*)(xn + (size_t)row * DIM))[tid] = o2;
  xs[2 * tid] = o2.x; xs[2 * tid + 1] = o2.y;
  __syncthreads();
  if (tid < 32) {  // 32 slots of 16B per row (k-permuted fp8)
    int c = tid >> 2, t4 = tid & 3;
    int k0 = c * 64 + t4 * 8;
    int4 w;
    w.x = pk4(xs[k0+0]*FP8SCALE, xs[k0+1]*FP8SCALE, xs[k0+2]*FP8SCALE, xs[k0+3]*FP8SCALE);
    w.y = pk4(xs[k0+4]*FP8SCALE, xs[k0+5]*FP8SCALE, xs[k0+6]*FP8SCALE, xs[k0+7]*FP8SCALE);
    w.z = pk4(xs[k0+32]*FP8SCALE, xs[k0+33]*FP8SCALE, xs[k0+34]*FP8SCALE, xs[k0+35]*FP8SCALE);
    w.w = pk4(xs[k0+36]*FP8SCALE, xs[k0+37]*FP8SCALE, xs[k0+38]*FP8SCALE, xs[k0+39]*FP8SCALE);
    ((int4*)(xnb8 + (size_t)row * DIM))[tid] = w;
  }
}

// ---------------------- fp8 MFMA GEMM + in-kernel B conversion + filter
// R18 schedule (proven 183.9us, absmax 0) widened to BN=128 with 8 waves
// (512 thr): grid halves (4096 blocks) -> A L2 traffic halves (1GB->0.5GB),
// gload_lds issue per FLOP halves. Wave-tile stays 64x64 (4M x 2N waves;
// acc 64 f32, no spill). LDS 48 KiB; lb(512,4) -> 2 blocks/CU = 16
// waves/CU (same occupancy as R18).
// Per-step queue (stageA = 2 loads, issuePB = 4 loads), counted vmcnt by
// enumeration:
//   prologue: issuePB(0)x4, stageA(0)x2; vmcnt(2) retires PB(0) only;
//             writeB(0); issuePB(1); lgkm0
//   pt1: queue [A(h)x2, PB(h+1)x4] -> vmcnt(4) retires A(h)   (h=7: 0)
//   pt2: stageA(h+1)x2                                        [h<7]
//   pt3: ds_read A x4 + B x4 (b128); 32 MFMA (setprio wrap)
//   pt4: queue [PB(h+1)x4, A(h+1)x2] -> vmcnt(2) retires PB(h+1);
//        writeB(h+1) [h<7]; issuePB(h+2) [h<6]; lgkm0
// Race proofs identical in structure to R15/R18 (lgkm0-before-barrier for
// LDS WAR; in-order vmcnt retirement for landing guarantees). Swizzle
// involution unchanged: phys = g ^ ((L>>1)&3) read-side, sg source-side
// (0 conflicts measured R6-R18).
// NOTE (R13/R16): 32x32 fp8 shapes incompatible with this layout. NOTE
// (R17): mid-step writeB / no-setprio / 8-lane rescore all regress.
__global__ __launch_bounds__(512, 4) void gemm_filter(const u8* __restrict__ xnb8,
                                                      const float* __restrict__ mem,
                                                      int* __restrict__ cnt,
                                                      int* __restrict__ ccol) {
  __shared__ __attribute__((aligned(16))) u8 As[2][16384];
  __shared__ __attribute__((aligned(16))) u8 Bs[2][8192];
  int bid = blockIdx.x;
  // XCD-aware: the 4 row-sharers of a B-panel sit on one XCD
  int xcd = bid & 7;
  int i = bid >> 3;
  int colt = xcd * 128 + (i >> 2);
  int rowt = i & 3;
  int row0 = rowt * 256;
  int col0 = colt * 128;
  int tid = threadIdx.x;
  int lane = tid & 63;
  int wv = tid >> 6;          // 0..7
  int wr = wv >> 1, wc = wv & 1;

  // staging geometry: logical k-slot sg = (tid&3) ^ ((r>>1)&3); A chunk jj
  // covers row r = jj*128 + (tid>>2) ((r>>1)&3 == (tid>>3)&3 for both jj);
  // B covers row r = tid>>2 (one 16B unit per thread).
  int sg = (tid & 3) ^ ((tid >> 3) & 3);
  const u8* gAb = xnb8 + (size_t)(row0 + (tid >> 2)) * DIM + sg * 16;
  const float* gB = mem + (size_t)(col0 + (tid >> 2)) * DIM + sg * 8;

  // read side: lane L = row-within-16; phys slot = g ^ ((L>>1)&3)
  int L = lane & 15;
  int g = lane >> 4;
  int phys = g ^ ((L >> 1) & 3);
  int offA = (wr * 64 + L) * 64 + phys * 16;   // bytes, + m*1024
  int offB = (wc * 64 + L) * 64 + phys * 16;   // bytes, + n*1024

  f32x4 acc[4][4];
  #pragma unroll
  for (int m = 0; m < 4; ++m)
    #pragma unroll
    for (int n = 0; n < 4; ++n) acc[m][n] = (f32x4){0.f, 0.f, 0.f, 0.f};

  float4 pb[4];  // B prefetch regs: 16 floats (16 VGPR)

  auto stageA = [&](int h) {
    int slot = h & 1;
    #pragma unroll
    for (int jj = 0; jj < 2; ++jj)
      gload_lds16(gAb + (size_t)jj * 65536 + h * 64,
                  &As[slot][jj * 8192 + tid * 16]);
  };
  auto issuePB = [&](int h) {
    const float4* s = (const float4*)(gB + h * 64);
    pb[0] = s[0]; pb[1] = s[1];   // k sg*8..+8
    pb[2] = s[8]; pb[3] = s[9];   // k 32+sg*8..+8
  };
  auto writeB = [&](int h) {
    int slot = h & 1;
    int4 w;
    w.x = pk4(pb[0].x*FP8SCALE, pb[0].y*FP8SCALE, pb[0].z*FP8SCALE, pb[0].w*FP8SCALE);
    w.y = pk4(pb[1].x*FP8SCALE, pb[1].y*FP8SCALE, pb[1].z*FP8SCALE, pb[1].w*FP8SCALE);
    w.z = pk4(pb[2].x*FP8SCALE, pb[2].y*FP8SCALE, pb[2].z*FP8SCALE, pb[2].w*FP8SCALE);
    w.w = pk4(pb[3].x*FP8SCALE, pb[3].y*FP8SCALE, pb[3].z*FP8SCALE, pb[3].w*FP8SCALE);
    *(int4*)&Bs[slot][tid * 16] = w;
  };

  union I4L { int4 v; long l[2]; };

  // prologue: PB(0) first, then A(0); vmcnt(2) retires PB(0) only (A(0)
  // keeps flying -- retired by loop-h0's vmcnt(4)+barrier).
  issuePB(0); stageA(0);
  S_VMCNT(2);
  writeB(0);
  issuePB(1);
  S_LGKM0();

  #pragma unroll
  for (int h = 0; h < 8; ++h) {
    if (h < 7) { S_VMCNT(4); }   // retires A(h)x2; keeps PB(h+1)x4 flying
    else { S_VMCNT(0); }         // h=7: drains A(7)
    S_BAR();
    if (h < 7) stageA(h + 1);
    const u8* Ab = &As[h & 1][0];
    const u8* Bb = &Bs[h & 1][0];
    I4L av[4], bv[4];
    #pragma unroll
    for (int m = 0; m < 4; ++m) av[m].v = *(const int4*)(Ab + offA + m * 1024);
    #pragma unroll
    for (int n = 0; n < 4; ++n) bv[n].v = *(const int4*)(Bb + offB + n * 1024);
    __builtin_amdgcn_s_setprio(1);
    #pragma unroll
    for (int m = 0; m < 4; ++m)
      #pragma unroll
      for (int n = 0; n < 4; ++n)
        acc[m][n] = __builtin_amdgcn_mfma_f32_16x16x32_fp8_fp8(
            av[m].l[0], bv[n].l[0], acc[m][n], 0, 0, 0);
    #pragma unroll
    for (int m = 0; m < 4; ++m)
      #pragma unroll
      for (int n = 0; n < 4; ++n)
        acc[m][n] = __builtin_amdgcn_mfma_f32_16x16x32_fp8_fp8(
            av[m].l[1], bv[n].l[1], acc[m][n], 0, 0, 0);
    __builtin_amdgcn_s_setprio(0);
    if (h < 7) {
      S_VMCNT(2);                // retires PB(h+1)x4; keeps A(h+1)x2 flying
      writeB(h + 1);
      if (h < 6) issuePB(h + 2);
      S_LGKM0();                 // ds ops retired before next barrier
    }
  }

  // epilogue: D row=(lane>>4)*4+q, col=lane&15 (dtype-independent layout)
  int rbase = row0 + wr * 64 + (lane >> 4) * 4;
  int cbase = col0 + wc * 64 + (lane & 15);
  #pragma unroll
  for (int m = 0; m < 4; ++m)
    #pragma unroll
    for (int n = 0; n < 4; ++n)
      #pragma unroll
      for (int q = 0; q < 4; ++q) {
        float v = acc[m][n][q];
        if (v > TAUS) {
          int grow = rbase + m * 16 + q;
          int gcol = cbase + n * 16;
          int idx = atomicAdd(&cnt[grow], 1);
          if (idx < CAP) ccol[(size_t)grow * CAP + idx] = gcol;
        }
      }
}

// ------------------------------- exact rescore + top-32 + softmax vote
// (R15 VERBATIM -- validated absmax 0.0; 16-lane groups: R17 showed 8-lane
// regresses ~+19us)
__global__ __launch_bounds__(256) void rescore_vote(const float* __restrict__ xn,
                                                    const float* __restrict__ mem,
                                                    const int* __restrict__ labels,
                                                    const int* __restrict__ cnt,
                                                    const int* __restrict__ ccol,
                                                    float* __restrict__ out) {
  int row = blockIdx.x;
  int tid = threadIdx.x;
  int gid = tid >> 4;          // 16 groups
  int gl = tid & 15;           // lane within group
  __shared__ __attribute__((aligned(16))) float xs[DIM];
  __shared__ double sv[CAP];
  __shared__ int sc[CAP];
  __shared__ double selv[TOPK];
  __shared__ int selc[TOPK];
  __shared__ double wv32[TOPK];
  __shared__ int slab[TOPK];

  ((float2*)xs)[tid] = ((const float2*)(xn + (size_t)row * DIM))[tid];
  if (tid < TOPK) { selv[tid] = -1e300; selc[tid] = 0; }
  int count = cnt[row];
  if (count > CAP) count = CAP;
  __syncthreads();

  // dot phase: one 16-lane group per candidate, fp64 accumulate
  for (int c = gid; c < count; c += 16) {
    int col = ccol[(size_t)row * CAP + c];
    const float4* mp = (const float4*)(mem + (size_t)col * DIM);
    const float4* xp = (const float4*)xs;
    double p = 0.0;
    #pragma unroll
    for (int u = 0; u < 8; ++u) {
      float4 mv = mp[u * 16 + gl];
      float4 xv = xp[u * 16 + gl];
      p += (double)mv.x * xv.x + (double)mv.y * xv.y +
           (double)mv.z * xv.z + (double)mv.w * xv.w;
    }
    #pragma unroll
    for (int o = 8; o; o >>= 1) p += __shfl_xor(p, o);
    if (gl == 0) { sv[c] = p; sc[c] = col; }
  }
  __syncthreads();

  // rank-based top-32: rank = #{j: v_j > v or (v_j==v && col_j < col)}
  for (int c = tid; c < count; c += 256) {
    double v = sv[c]; int cc = sc[c];
    int r = 0;
    for (int j = 0; j < count; ++j) {
      double vj = sv[j]; int cj = sc[j];
      r += (vj > v) || (vj == v && cj < cc);
    }
    if (r < TOPK) { selv[r] = v; selc[r] = cc; }
  }
  __syncthreads();

  // softmax(sim/0.1) + one-hot vote
  if (tid < TOPK) {
    slab[tid] = labels[selc[tid]];
    double e = exp((selv[tid] - selv[0]) * 10.0);
    double s = e;
    #pragma unroll
    for (int o = 16; o; o >>= 1) s += __shfl_xor(s, o, 32);
    wv32[tid] = e / s;
  }
  __syncthreads();
  if (tid < NCLS) {
    double a = 0.0;
    #pragma unroll
    for (int k = 0; k < TOPK; ++k)
      if (slab[k] == tid) a += wv32[k];
    float r2 = (float)(a + 1e-5);
    out[(size_t)row * NCLS + tid] = fminf(r2, 1.0f);
  }
}

// ---------------------------------------------------------------------------
extern "C" void kernel_launch(void* const* d_in, const int* in_sizes, int n_in,
                              void* d_out, int out_size, void* d_ws, size_t ws_size,
                              hipStream_t stream) {
  const float* x = (const float*)d_in[0];
  const float* mem = (const float*)d_in[1];
  const int* labels = (const int*)d_in[2];
  float* out = (float*)d_out;
  char* ws = (char*)d_ws;

  // workspace layout (needs ~7 MB)
  float* xn = (float*)ws;                            //   2,097,152 B
  u8* xnb8 = (u8*)(ws + 2097152);                    //     524,288 B
  int* cnt = (int*)(ws + 2621440);                   //       4,096 B
  int* ccol = (int*)(ws + 2625536);                  //   4,194,304 B

  normalize_x<<<dim3(B_ROWS), dim3(256), 0, stream>>>(x, xn, xnb8, cnt);
  gemm_filter<<<dim3((B_ROWS / 256) * (QN / 128)), dim3(512), 0, stream>>>(
      xnb8, mem, cnt, ccol);
  rescore_vote<<<dim3(B_ROWS), dim3(256), 0, stream>>>(xn, mem, labels, cnt,
                                                       ccol, out);
}